// Round 6
// baseline (317.363 us; speedup 1.0000x reference)
//
#include <hip/hip_runtime.h>

typedef unsigned short ushort;
typedef unsigned int uint;

typedef __bf16 bf16x8 __attribute__((ext_vector_type(8)));
typedef float floatx4 __attribute__((ext_vector_type(4)));

constexpr int BATCH = 4;
constexpr int SEQ = 2048;
constexpr int DM = 1024;
constexpr int NH = 16;
constexpr int HD = 64;
constexpr int M = BATCH * SEQ;   // 8192 rows
constexpr int NQKV = 3 * DM;     // 3072
constexpr float QSCALE = 0.18033688011112042f;   // log2(e) / sqrt(dm/h)

__device__ __forceinline__ ushort f2b(float f) {
    uint x; __builtin_memcpy(&x, &f, 4);
    x += 0x7fffu + ((x >> 16) & 1u);   // RTNE (finite values)
    return (ushort)(x >> 16);
}

__device__ __forceinline__ void gload16(const ushort* g, ushort* l) {
    __builtin_amdgcn_global_load_lds(
        (const __attribute__((address_space(1))) void*)g,
        (__attribute__((address_space(3))) void*)l, 16, 0, 0);
}

// ------------------------- merged prep: weight transposes + LayerNorm
__global__ __launch_bounds__(256) void prep_kernel(
    const float* __restrict__ w_qkv, ushort* __restrict__ wqT,
    const float* __restrict__ w_proj, ushort* __restrict__ wpT,
    const float* __restrict__ z, const float* __restrict__ gamma,
    const float* __restrict__ beta, ushort* __restrict__ zn) {
    __shared__ ushort tile[64][65];
    int id = blockIdx.x;
    int t = threadIdx.x;
    if (id < 1024) {
        int tx = t & 63, ty = t >> 6;
        if (id < 768) {
            int bx = id % 48, by = id / 48;
            int c0 = bx * 64, r0 = by * 64;
#pragma unroll
            for (int i = 0; i < 64; i += 4)
                tile[i + ty][tx] = f2b(w_qkv[(size_t)(r0 + i + ty) * NQKV + c0 + tx]);
            __syncthreads();
#pragma unroll
            for (int i = 0; i < 64; i += 4) {
                int c = c0 + i + ty;
                int cp = (c % 3) * DM + c / 3;
                wqT[(size_t)cp * DM + r0 + tx] = tile[tx][i + ty];
            }
        } else {
            int q = id - 768;
            int c0 = (q % 16) * 64, r0 = (q / 16) * 64;
#pragma unroll
            for (int i = 0; i < 64; i += 4)
                tile[i + ty][tx] = f2b(w_proj[(size_t)(r0 + i + ty) * DM + c0 + tx]);
            __syncthreads();
#pragma unroll
            for (int i = 0; i < 64; i += 4)
                wpT[(size_t)(c0 + i + ty) * DM + r0 + tx] = tile[tx][i + ty];
        }
        return;
    }
    // ---- LayerNorm
    int row = id - 1024;
    float4 v = reinterpret_cast<const float4*>(z + (size_t)row * DM)[t];
    float s = v.x + v.y + v.z + v.w;
    float sq = v.x * v.x + v.y * v.y + v.z * v.z + v.w * v.w;
#pragma unroll
    for (int off = 32; off >= 1; off >>= 1) {
        s  += __shfl_xor(s, off);
        sq += __shfl_xor(sq, off);
    }
    __shared__ float red[8];
    int wave = t >> 6;
    if ((t & 63) == 0) { red[wave] = s; red[wave + 4] = sq; }
    __syncthreads();
    s  = red[0] + red[1] + red[2] + red[3];
    sq = red[4] + red[5] + red[6] + red[7];
    float mean = s * (1.f / DM);
    float var  = sq * (1.f / DM) - mean * mean;
    float rstd = rsqrtf(var + 1e-5f);
    float4 g = reinterpret_cast<const float4*>(gamma)[t];
    float4 bt = reinterpret_cast<const float4*>(beta)[t];
    ushort4 o;
    o.x = f2b((v.x - mean) * rstd * g.x + bt.x);
    o.y = f2b((v.y - mean) * rstd * g.y + bt.y);
    o.z = f2b((v.z - mean) * rstd * g.z + bt.z);
    o.w = f2b((v.w - mean) * rstd * g.w + bt.w);
    reinterpret_cast<ushort4*>(zn + (size_t)row * DM)[t] = o;
}

// ----------------------------------------------------------- 128x128 GEMM core
// (kept for gemm_proj)
__device__ __forceinline__ void gemm128_core(
    const ushort* __restrict__ A, const ushort* __restrict__ BT,
    int m0, int n0, int t, floatx4 (&acc)[4][4],
    ushort (*As)[64], ushort (*Bs)[64]) {
    int lane = t & 63, w = t >> 6;
    int l16 = lane & 15, quad = lane >> 4;
    int wm = (w >> 1) * 64, wn = (w & 1) * 64;
#pragma unroll
    for (int i = 0; i < 4; i++)
#pragma unroll
        for (int j = 0; j < 4; j++) acc[i][j] = (floatx4){0.f, 0.f, 0.f, 0.f};

    int srow8 = lane >> 3;                 // row within 8-row wave chunk
    int lseg = (lane & 7) ^ srow8;         // logical k-segment (XOR swizzle)
    const ushort* gA[4]; const ushort* gB[4];
    ushort* lA[4]; ushort* lB[4];
#pragma unroll
    for (int c = 0; c < 4; c++) {
        int r = 32 * c + 8 * w + srow8;
        gA[c] = &A [(size_t)(m0 + r) * DM + lseg * 8];
        gB[c] = &BT[(size_t)(n0 + r) * DM + lseg * 8];
        lA[c] = &As[32 * c + 8 * w][0];    // wave-uniform LDS bases
        lB[c] = &Bs[32 * c + 8 * w][0];
    }
    int sw = l16 & 7;                      // read-side swizzle (row&7 = l16&7)

    for (int k0 = 0; k0 < DM; k0 += 64) {
#pragma unroll
        for (int c = 0; c < 4; c++) {
            gload16(gA[c] + k0, lA[c]);
            gload16(gB[c] + k0, lB[c]);
        }
        __syncthreads();
#pragma unroll
        for (int kk = 0; kk < 2; kk++) {
            bf16x8 af[4], bf[4];
#pragma unroll
            for (int i = 0; i < 4; i++)
                af[i] = *reinterpret_cast<const bf16x8*>(
                    &As[wm + i * 16 + l16][((kk * 4 + quad) ^ sw) << 3]);
#pragma unroll
            for (int j = 0; j < 4; j++)
                bf[j] = *reinterpret_cast<const bf16x8*>(
                    &Bs[wn + j * 16 + l16][((kk * 4 + quad) ^ sw) << 3]);
#pragma unroll
            for (int i = 0; i < 4; i++)
#pragma unroll
                for (int j = 0; j < 4; j++)
                    acc[i][j] = __builtin_amdgcn_mfma_f32_16x16x32_bf16(
                        af[i], bf[j], acc[i][j], 0, 0, 0);
        }
        __syncthreads();
    }
}

// ------------------------------------------- 256x256 8-wave GEMM1, per-phase
__global__ __launch_bounds__(512) void gemm_qkv256(
    const ushort* __restrict__ A,    // zn [M][DM]
    const ushort* __restrict__ BT,   // w_qkv^T reordered [3*DM][DM]
    ushort* __restrict__ Q, ushort* __restrict__ K, ushort* __restrict__ V) {
    __shared__ ushort smem[65536];   // 128 KB
    int t = threadIdx.x;
    int lane = t & 63, w = t >> 6;
    int l16 = lane & 15, quad = lane >> 4;
    int wm = w >> 2, wn = w & 3;     // wave grid 2M x 4N
    int id = blockIdx.x;
    int m0 = (id & 31) * 256, n0 = (id >> 5) * 256;

    // staging source addresses (pre-swizzled segment)
    int srow = t >> 3;                       // 0..63
    int sseg = (t & 7) ^ (srow & 7);
    const ushort* gA[4]; const ushort* gB[4];
#pragma unroll
    for (int c = 0; c < 4; c++) {
        int r = c * 64 + srow;
        gA[c] = A  + (size_t)(m0 + r) * DM + sseg * 8;
        gB[c] = BT + (size_t)(n0 + r) * DM + sseg * 8;
    }
    int wbase = w * 512;                     // wave-uniform LDS chunk base

    auto stage = [&](int k0, int d) {
        int ab = d * 16384, bb2 = 32768 + d * 16384;
#pragma unroll
        for (int c = 0; c < 4; c++) {
            gload16(gA[c] + k0, &smem[ab  + c * 4096 + wbase]);
            gload16(gB[c] + k0, &smem[bb2 + c * 4096 + wbase]);
        }
    };

    floatx4 acc[8][4];
#pragma unroll
    for (int i = 0; i < 8; i++)
#pragma unroll
        for (int j = 0; j < 4; j++) acc[i][j] = (floatx4){0.f, 0.f, 0.f, 0.f};

    int sw = l16 & 7;                        // read-side swizzle

    stage(0, 0);                             // tile 0 -> dbuf0
    for (int kt = 0; kt < 16; kt++) {
        int d = kt & 1;
        int ab = d * 16384, bb2 = 32768 + d * 16384;

        // ---- tile top: dbuf[d] data landed + visible to all waves
        asm volatile("s_waitcnt vmcnt(0)" ::: "memory");
        __builtin_amdgcn_s_barrier();

        // ---- phase 0: B frags (whole tile) + A rows {0,1}; stage burst
        bf16x8 bf[4][2];
#pragma unroll
        for (int j = 0; j < 4; j++)
#pragma unroll
            for (int kk = 0; kk < 2; kk++)
                bf[j][kk] = *reinterpret_cast<const bf16x8*>(
                    &smem[bb2 + (wn * 64 + j * 16 + l16) * 64 +
                          (((kk * 4 + quad) ^ sw) << 3)]);
        bf16x8 af[2][2];
#pragma unroll
        for (int ii = 0; ii < 2; ii++)
#pragma unroll
            for (int kk = 0; kk < 2; kk++)
                af[ii][kk] = *reinterpret_cast<const bf16x8*>(
                    &smem[ab + (wm * 128 + ii * 16 + l16) * 64 +
                          (((kk * 4 + quad) ^ sw) << 3)]);
        if (kt + 1 < 16) stage((kt + 1) * 64, d ^ 1);
        __builtin_amdgcn_s_barrier();
        asm volatile("s_waitcnt lgkmcnt(0)" ::: "memory");
        __builtin_amdgcn_sched_barrier(0);
        __builtin_amdgcn_s_setprio(1);
#pragma unroll
        for (int ii = 0; ii < 2; ii++)
#pragma unroll
            for (int kk = 0; kk < 2; kk++)
#pragma unroll
                for (int j = 0; j < 4; j++)
                    acc[ii][j] = __builtin_amdgcn_mfma_f32_16x16x32_bf16(
                        af[ii][kk], bf[j][kk], acc[ii][j], 0, 0, 0);
        __builtin_amdgcn_s_setprio(0);

        // ---- phases 1..3: A rows {2p,2p+1}
#pragma unroll
        for (int p = 1; p < 4; p++) {
#pragma unroll
            for (int ii = 0; ii < 2; ii++)
#pragma unroll
                for (int kk = 0; kk < 2; kk++)
                    af[ii][kk] = *reinterpret_cast<const bf16x8*>(
                        &smem[ab + (wm * 128 + (2 * p + ii) * 16 + l16) * 64 +
                              (((kk * 4 + quad) ^ sw) << 3)]);
            __builtin_amdgcn_s_barrier();
            asm volatile("s_waitcnt lgkmcnt(0)" ::: "memory");
            __builtin_amdgcn_sched_barrier(0);
            __builtin_amdgcn_s_setprio(1);
#pragma unroll
            for (int ii = 0; ii < 2; ii++)
#pragma unroll
                for (int kk = 0; kk < 2; kk++)
#pragma unroll
                    for (int j = 0; j < 4; j++)
                        acc[2 * p + ii][j] = __builtin_amdgcn_mfma_f32_16x16x32_bf16(
                            af[ii][kk], bf[j][kk], acc[2 * p + ii][j], 0, 0, 0);
            __builtin_amdgcn_s_setprio(0);
        }
    }
    asm volatile("s_waitcnt lgkmcnt(0)\n\ts_barrier" ::: "memory");

    // ---------------- epilogue: LDS bounce in two 128-row half passes
    int which = n0 >> 10;            // 0=Q 1=K 2=V (256 | 1024 -> uniform)
    int hd0 = n0 & 1023;
    int bbx = m0 >> 11;              // batch (256 | 2048: never crosses)
    int nb = m0 & 2047;
    float scale = (which == 0) ? QSCALE : 1.0f;

    if (which < 2) {
        ushort* dst = (which == 0) ? Q : K;
#pragma unroll
        for (int p = 0; p < 2; p++) {
            if (wm == p) {           // waves owning rows p*128..p*128+127
#pragma unroll
                for (int i = 0; i < 8; i++)
#pragma unroll
                    for (int j = 0; j < 4; j++)
#pragma unroll
                        for (int r = 0; r < 4; r++)
                            smem[(i * 16 + quad * 4 + r) * 264 + wn * 64 + j * 16 + l16] =
                                f2b(acc[i][j][r] * scale);
            }
            asm volatile("s_waitcnt lgkmcnt(0)\n\ts_barrier" ::: "memory");
            int ch = (t & 31) * 8;   // col chunk base (0..248)
#pragma unroll
            for (int u = 0; u < 8; u++) {
                int r = (t >> 5) + u * 16;
                int n = nb + p * 128 + r;
                int col = hd0 + ch;
                int hh = col >> 6, dd = col & 63;
                *reinterpret_cast<uint4*>(
                    &dst[((size_t)((bbx * NH + hh) * SEQ) + n) * HD + dd]) =
                    *reinterpret_cast<const uint4*>(&smem[r * 264 + ch]);
            }
            asm volatile("s_waitcnt lgkmcnt(0)\n\ts_barrier" ::: "memory");
        }
    } else {                         // V: transposed bounce [dcol][n_local]
#pragma unroll
        for (int p = 0; p < 2; p++) {
            if (wm == p) {
#pragma unroll
                for (int i = 0; i < 8; i++)
#pragma unroll
                    for (int j = 0; j < 4; j++)
#pragma unroll
                        for (int r = 0; r < 4; r++)
                            smem[(wn * 64 + j * 16 + l16) * 136 + i * 16 + quad * 4 + r] =
                                f2b(acc[i][j][r]);
            }
            asm volatile("s_waitcnt lgkmcnt(0)\n\ts_barrier" ::: "memory");
            int nch = (t & 15) * 8;  // n chunk base (0..120)
#pragma unroll
            for (int u = 0; u < 8; u++) {
                int dc = (t >> 4) + u * 32;
                int hh = (hd0 >> 6) + (dc >> 6), dd = dc & 63;
                int n = nb + p * 128 + nch;
                *reinterpret_cast<uint4*>(
                    &V[((size_t)((bbx * NH + hh) * HD) + dd) * SEQ + n]) =
                    *reinterpret_cast<const uint4*>(&smem[dc * 136 + nch]);
            }
            asm volatile("s_waitcnt lgkmcnt(0)\n\ts_barrier" ::: "memory");
        }
    }
}

// GEMM2: O @ w_proj + b_proj + z -> out (fp32).  1D grid, id%8 = m%8.
__global__ __launch_bounds__(256) void gemm_proj(
    const ushort* __restrict__ A,    // O [M][DM]
    const ushort* __restrict__ BT,   // w_proj^T [DM][DM]
    const float* __restrict__ bias, const float* __restrict__ z,
    float* __restrict__ out) {
    __shared__ ushort As[128][64];
    __shared__ ushort Bs[128][64];
    int t = threadIdx.x;
    int id = blockIdx.x;
    int m0 = (id & 63) * 128, n0 = (id >> 6) * 128;
    floatx4 acc[4][4];
    gemm128_core(A, BT, m0, n0, t, acc, As, Bs);
    int lane = t & 63, w = t >> 6;
    int l16 = lane & 15, quad = lane >> 4;
    int wm = (w >> 1) * 64, wn = (w & 1) * 64;
#pragma unroll
    for (int j = 0; j < 4; j++) {
        int col = n0 + wn + j * 16 + l16;
        float bz = bias[col];
#pragma unroll
        for (int i = 0; i < 4; i++) {
#pragma unroll
            for (int r = 0; r < 4; r++) {
                int row = m0 + wm + i * 16 + quad * 4 + r;
                out[(size_t)row * DM + col] =
                    acc[i][j][r] + bz + z[(size_t)row * DM + col];
            }
        }
    }
}

// --------------------------------------------------------- Flash attention
// One block per (b,h, 256-row Q tile); wave owns 64 q-rows (4 groups of 16).
// Doubled q-per-wave halves LDS ops per MFMA (K/V fragment reads amortized
// over 2x MFMA) — attacks the measured ~90%-busy LDS pipe.  QK runs in two
// g-pairs (K frags re-read once) to keep sacc register pressure at [2][4].
// LDS = 48 KB; grid 512 = 2.0 blocks/CU exactly (no tail).
// Block id = qt*64 + bh -> id%8 = bh%8: same-head blocks share an XCD's L2.
__global__ __launch_bounds__(256) void attn_kernel(
    const ushort* __restrict__ Q, const ushort* __restrict__ K,
    const ushort* __restrict__ Vt, ushort* __restrict__ O) {
    __shared__ ushort QsPs[256 * 64];     // Q staging, then P [q][key] swizzled
    __shared__ ushort Ks[64 * 64];        // [key][d] swizzled (single buffer)
    __shared__ ushort Vs[64 * 64];        // [d][key] swizzled (single buffer)
    int t = threadIdx.x;
    int lane = t & 63, w = t >> 6;
    int l16 = lane & 15, quad = lane >> 4;
    int id = blockIdx.x;
    int qt = id >> 6, bh = id & 63;       // id%8 = bh%8 (XCD swizzle)
    int bb = bh >> 4, h = bh & 15;
    int q0 = qt * 256;
    const ushort* Qg = Q  + (size_t)((bb * NH + h) * SEQ + q0) * HD;
    const ushort* Kg = K  + (size_t)((bb * NH + h) * SEQ) * HD;
    const ushort* Vg = Vt + (size_t)((bb * NH + h) * HD) * SEQ;

    int srow = lane >> 3;                 // row within wave chunk (0..7)
    int lseg = (lane & 7) ^ srow;         // logical k-segment (XOR swizzle)
    int r0 = 8 * w + srow;                // row within 32-row chunk

    // Q staging (DMA, once): 8 chunks of 32 rows; + K/V tile 0 (DMA)
#pragma unroll
    for (int c = 0; c < 8; c++)
        gload16(Qg + (size_t)(32 * c + r0) * HD + lseg * 8, &QsPs[c * 2048 + w * 512]);
    gload16(Kg + (size_t)r0 * HD + lseg * 8,         &Ks[w * 512]);
    gload16(Kg + (size_t)(32 + r0) * HD + lseg * 8,  &Ks[2048 + w * 512]);
    gload16(Vg + (size_t)r0 * SEQ + lseg * 8,        &Vs[w * 512]);
    gload16(Vg + (size_t)(32 + r0) * SEQ + lseg * 8, &Vs[2048 + w * 512]);
    __syncthreads();

    int swl = l16 & 7;                    // read-side swizzle (row&7 = l16&7)
    bf16x8 aq[4][2];
    ushort* PsRow[4];
#pragma unroll
    for (int g = 0; g < 4; g++) {
        int row = 64 * w + 16 * g + l16;
        aq[g][0] = *reinterpret_cast<const bf16x8*>(&QsPs[row * 64 + ((quad ^ swl) << 3)]);
        aq[g][1] = *reinterpret_cast<const bf16x8*>(&QsPs[row * 64 + (((quad + 4) ^ swl) << 3)]);
        PsRow[g] = &QsPs[row * 64];
    }

    // per-thread prefetch source offsets (tile-relative) and LDS commit slots
    size_t koff1 = (size_t)r0 * HD + lseg * 8;
    size_t koff2 = (size_t)(32 + r0) * HD + lseg * 8;
    size_t voff1 = (size_t)r0 * SEQ + lseg * 8;
    size_t voff2 = (size_t)(32 + r0) * SEQ + lseg * 8;
    ushort* kw1 = &Ks[w * 512 + lane * 8];
    ushort* kw2 = &Ks[2048 + w * 512 + lane * 8];
    ushort* vw1 = &Vs[w * 512 + lane * 8];
    ushort* vw2 = &Vs[2048 + w * 512 + lane * 8];
    const ushort* Kp = Kg + (size_t)64 * HD;   // next-tile base (tile 1)
    const ushort* Vp = Vg + 64;

    bf16x8 bones;
    {
        union { ushort u[8]; bf16x8 v; } cvt;
        ushort one = (l16 == 0) ? (ushort)0x3F80 : (ushort)0;
#pragma unroll
        for (int i = 0; i < 8; i++) cvt.u[i] = one;
        bones = cvt.v;
    }

    floatx4 Oacc[4][4], lacc[4];
#pragma unroll
    for (int g = 0; g < 4; g++) {
        lacc[g] = (floatx4){0.f, 0.f, 0.f, 0.f};
#pragma unroll
        for (int tt = 0; tt < 4; tt++) Oacc[g][tt] = (floatx4){0.f, 0.f, 0.f, 0.f};
    }

    constexpr int NT = SEQ / 64;
    for (int kt = 0; kt < NT; kt++) {
        // register prefetch of tile kt+1 (one-past read on last iter is
        // in-bounds of the workspace and never consumed)
        uint4 kr1 = *reinterpret_cast<const uint4*>(Kp + koff1);
        uint4 kr2 = *reinterpret_cast<const uint4*>(Kp + koff2);
        uint4 vr1 = *reinterpret_cast<const uint4*>(Vp + voff1);
        uint4 vr2 = *reinterpret_cast<const uint4*>(Vp + voff2);
        Kp += (size_t)64 * HD;
        Vp += 64;

        // S^T = K Q^T in two g-pairs (bounds sacc at [2][4]); K frags
        // shared across the pair's groups.
#pragma unroll
        for (int gp = 0; gp < 2; gp++) {
            floatx4 sacc[2][4];
#pragma unroll
            for (int nt = 0; nt < 4; nt++) {
                bf16x8 ak0 = *reinterpret_cast<const bf16x8*>(&Ks[(nt * 16 + l16) * 64 + ((quad ^ swl) << 3)]);
                bf16x8 ak1 = *reinterpret_cast<const bf16x8*>(&Ks[(nt * 16 + l16) * 64 + (((quad + 4) ^ swl) << 3)]);
#pragma unroll
                for (int gg = 0; gg < 2; gg++) {
                    floatx4 sv = (floatx4){0.f, 0.f, 0.f, 0.f};
                    sv = __builtin_amdgcn_mfma_f32_16x16x32_bf16(ak0, aq[2 * gp + gg][0], sv, 0, 0, 0);
                    sv = __builtin_amdgcn_mfma_f32_16x16x32_bf16(ak1, aq[2 * gp + gg][1], sv, 0, 0, 0);
                    sacc[gg][nt] = sv;
                }
            }
            // p = exp2(S^T); truncate-pack pairs; write P[q][key] swizzled b64
#pragma unroll
            for (int gg = 0; gg < 2; gg++) {
#pragma unroll
                for (int nt = 0; nt < 4; nt++) {
                    float p0 = __builtin_amdgcn_exp2f(sacc[gg][nt][0]);
                    float p1 = __builtin_amdgcn_exp2f(sacc[gg][nt][1]);
                    float p2 = __builtin_amdgcn_exp2f(sacc[gg][nt][2]);
                    float p3 = __builtin_amdgcn_exp2f(sacc[gg][nt][3]);
                    uint b0, b1, b2, b3;
                    __builtin_memcpy(&b0, &p0, 4); __builtin_memcpy(&b1, &p1, 4);
                    __builtin_memcpy(&b2, &p2, 4); __builtin_memcpy(&b3, &p3, 4);
                    uint2 pk;
                    pk.x = __builtin_amdgcn_perm(b1, b0, 0x07060302u);  // truncate-pack
                    pk.y = __builtin_amdgcn_perm(b3, b2, 0x07060302u);
                    int lseg2 = 2 * nt + (quad >> 1);
                    *reinterpret_cast<uint2*>(
                        &PsRow[2 * gp + gg][((lseg2 ^ swl) << 3) + (quad & 1) * 4]) = pk;
                }
            }
        }
        // O += P V ; row-sums via ones-column MFMA; V frags shared across groups
#pragma unroll
        for (int ks = 0; ks < 2; ks++) {
            bf16x8 ap[4];
#pragma unroll
            for (int g = 0; g < 4; g++) {
                ap[g] = *reinterpret_cast<const bf16x8*>(
                    &PsRow[g][(((4 * ks + quad) ^ swl) << 3)]);
                lacc[g] = __builtin_amdgcn_mfma_f32_16x16x32_bf16(ap[g], bones, lacc[g], 0, 0, 0);
            }
#pragma unroll
            for (int tt = 0; tt < 4; tt++) {
                bf16x8 bv = *reinterpret_cast<const bf16x8*>(
                    &Vs[(tt * 16 + l16) * 64 + ((((ks * 4 + quad)) ^ swl) << 3)]);
#pragma unroll
                for (int g = 0; g < 4; g++)
                    Oacc[g][tt] = __builtin_amdgcn_mfma_f32_16x16x32_bf16(ap[g], bv, Oacc[g][tt], 0, 0, 0);
            }
        }
        __syncthreads();              // all waves done reading Ks/Vs
        *reinterpret_cast<uint4*>(kw1) = kr1;
        *reinterpret_cast<uint4*>(kw2) = kr2;
        *reinterpret_cast<uint4*>(vw1) = vr1;
        *reinterpret_cast<uint4*>(vw2) = vr2;
        __syncthreads();              // next tile visible
    }
    float lq[4][4];
#pragma unroll
    for (int g = 0; g < 4; g++)
#pragma unroll
        for (int j = 0; j < 4; j++) lq[g][j] = __shfl(lacc[g][j], quad << 4);

#pragma unroll
    for (int g = 0; g < 4; g++) {
#pragma unroll
        for (int tt = 0; tt < 4; tt++) {
#pragma unroll
            for (int j = 0; j < 4; j++) {
                int n = q0 + 64 * w + 16 * g + quad * 4 + j;
                int dcol = tt * 16 + l16;
                float val = Oacc[g][tt][j] / lq[g][j];
                O[(size_t)(bb * SEQ + n) * DM + h * HD + dcol] = f2b(val);
            }
        }
    }
}

extern "C" void kernel_launch(void* const* d_in, const int* in_sizes, int n_in,
                              void* d_out, int out_size, void* d_ws, size_t ws_size,
                              hipStream_t stream) {
    const float* z      = (const float*)d_in[0];
    const float* gamma  = (const float*)d_in[1];
    const float* beta   = (const float*)d_in[2];
    const float* w_qkv  = (const float*)d_in[3];
    const float* w_proj = (const float*)d_in[4];
    const float* b_proj = (const float*)d_in[5];
    float* out = (float*)d_out;

    char* ws = (char*)d_ws;
    const size_t SZ = (size_t)M * DM * sizeof(ushort);   // 16 MiB
    ushort* zn   = (ushort*)(ws);                        // reused as attn output O
    ushort* Qb   = (ushort*)(ws + SZ);
    ushort* Kb   = (ushort*)(ws + 2 * SZ);
    ushort* Vb   = (ushort*)(ws + 3 * SZ);               // transposed [b,h,d,n]
    ushort* wqT  = (ushort*)(ws + 4 * SZ);               // reordered [3*DM][DM]
    ushort* wpT  = (ushort*)(ws + 4 * SZ + (size_t)DM * NQKV * sizeof(ushort));
    ushort* Ob = zn;   // zn dead after gemm_qkv

    prep_kernel<<<1024 + M, 256, 0, stream>>>(w_qkv, wqT, w_proj, wpT,
                                              z, gamma, beta, zn);
    gemm_qkv256<<<(M / 256) * (NQKV / 256), 512, 0, stream>>>(zn, wqT, Qb, Kb, Vb);
    attn_kernel<<<(SEQ / 256) * BATCH * NH, 256, 0, stream>>>(Qb, Kb, Vb, Ob);
    gemm_proj<<<(DM / 128) * 64, 256, 0, stream>>>(Ob, wpT, b_proj, z, out);
}

// Round 7
// 273.041 us; speedup vs baseline: 1.1623x; 1.1623x over previous
//
#include <hip/hip_runtime.h>

typedef unsigned short ushort;
typedef unsigned int uint;

typedef __bf16 bf16x8 __attribute__((ext_vector_type(8)));
typedef float floatx4 __attribute__((ext_vector_type(4)));

constexpr int BATCH = 4;
constexpr int SEQ = 2048;
constexpr int DM = 1024;
constexpr int NH = 16;
constexpr int HD = 64;
constexpr int M = BATCH * SEQ;   // 8192 rows
constexpr int NQKV = 3 * DM;     // 3072
constexpr float QSCALE = 0.18033688011112042f;   // log2(e) / sqrt(dm/h)

__device__ __forceinline__ ushort f2b(float f) {
    uint x; __builtin_memcpy(&x, &f, 4);
    x += 0x7fffu + ((x >> 16) & 1u);   // RTNE (finite values)
    return (ushort)(x >> 16);
}

__device__ __forceinline__ void gload16(const ushort* g, ushort* l) {
    __builtin_amdgcn_global_load_lds(
        (const __attribute__((address_space(1))) void*)g,
        (__attribute__((address_space(3))) void*)l, 16, 0, 0);
}

// ------------------------- merged prep: weight transposes + LayerNorm
// blocks [0,768): w_qkv fp32 [DM][NQKV] -> bf16 reordered-T [3*DM][DM]
//   (col c=(h*64+d)*3+s  ->  row' = s*1024 + h*64+d)
// blocks [768,1024): w_proj fp32 [DM][DM] -> bf16 T [DM][DM]
// blocks [1024,9216): LayerNorm row (fp32 in, bf16 out)
__global__ __launch_bounds__(256) void prep_kernel(
    const float* __restrict__ w_qkv, ushort* __restrict__ wqT,
    const float* __restrict__ w_proj, ushort* __restrict__ wpT,
    const float* __restrict__ z, const float* __restrict__ gamma,
    const float* __restrict__ beta, ushort* __restrict__ zn) {
    __shared__ ushort tile[64][65];
    int id = blockIdx.x;
    int t = threadIdx.x;
    if (id < 1024) {
        int tx = t & 63, ty = t >> 6;
        if (id < 768) {
            int bx = id % 48, by = id / 48;
            int c0 = bx * 64, r0 = by * 64;
#pragma unroll
            for (int i = 0; i < 64; i += 4)
                tile[i + ty][tx] = f2b(w_qkv[(size_t)(r0 + i + ty) * NQKV + c0 + tx]);
            __syncthreads();
#pragma unroll
            for (int i = 0; i < 64; i += 4) {
                int c = c0 + i + ty;
                int cp = (c % 3) * DM + c / 3;
                wqT[(size_t)cp * DM + r0 + tx] = tile[tx][i + ty];
            }
        } else {
            int q = id - 768;
            int c0 = (q % 16) * 64, r0 = (q / 16) * 64;
#pragma unroll
            for (int i = 0; i < 64; i += 4)
                tile[i + ty][tx] = f2b(w_proj[(size_t)(r0 + i + ty) * DM + c0 + tx]);
            __syncthreads();
#pragma unroll
            for (int i = 0; i < 64; i += 4)
                wpT[(size_t)(c0 + i + ty) * DM + r0 + tx] = tile[tx][i + ty];
        }
        return;
    }
    // ---- LayerNorm
    int row = id - 1024;
    float4 v = reinterpret_cast<const float4*>(z + (size_t)row * DM)[t];
    float s = v.x + v.y + v.z + v.w;
    float sq = v.x * v.x + v.y * v.y + v.z * v.z + v.w * v.w;
#pragma unroll
    for (int off = 32; off >= 1; off >>= 1) {
        s  += __shfl_xor(s, off);
        sq += __shfl_xor(sq, off);
    }
    __shared__ float red[8];
    int wave = t >> 6;
    if ((t & 63) == 0) { red[wave] = s; red[wave + 4] = sq; }
    __syncthreads();
    s  = red[0] + red[1] + red[2] + red[3];
    sq = red[4] + red[5] + red[6] + red[7];
    float mean = s * (1.f / DM);
    float var  = sq * (1.f / DM) - mean * mean;
    float rstd = rsqrtf(var + 1e-5f);
    float4 g = reinterpret_cast<const float4*>(gamma)[t];
    float4 bt = reinterpret_cast<const float4*>(beta)[t];
    ushort4 o;
    o.x = f2b((v.x - mean) * rstd * g.x + bt.x);
    o.y = f2b((v.y - mean) * rstd * g.y + bt.y);
    o.z = f2b((v.z - mean) * rstd * g.z + bt.z);
    o.w = f2b((v.w - mean) * rstd * g.w + bt.w);
    reinterpret_cast<ushort4*>(zn + (size_t)row * DM)[t] = o;
}

// ----------------------------------------------------------- 128x128 GEMM core
// BK=64 double-stage: 8 global_load_lds + one barrier pair per 64 k-elems.
// 8-segment XOR swizzle: phys = logical^(row&7); fragment b128 reads are
// 2-way (free) at unpadded 64-elem rows.
__device__ __forceinline__ void gemm128_core(
    const ushort* __restrict__ A, const ushort* __restrict__ BT,
    int m0, int n0, int t, floatx4 (&acc)[4][4],
    ushort (*As)[64], ushort (*Bs)[64]) {
    int lane = t & 63, w = t >> 6;
    int l16 = lane & 15, quad = lane >> 4;
    int wm = (w >> 1) * 64, wn = (w & 1) * 64;
#pragma unroll
    for (int i = 0; i < 4; i++)
#pragma unroll
        for (int j = 0; j < 4; j++) acc[i][j] = (floatx4){0.f, 0.f, 0.f, 0.f};

    int srow8 = lane >> 3;                 // row within 8-row wave chunk
    int lseg = (lane & 7) ^ srow8;         // logical k-segment (XOR swizzle)
    const ushort* gA[4]; const ushort* gB[4];
    ushort* lA[4]; ushort* lB[4];
#pragma unroll
    for (int c = 0; c < 4; c++) {
        int r = 32 * c + 8 * w + srow8;
        gA[c] = &A [(size_t)(m0 + r) * DM + lseg * 8];
        gB[c] = &BT[(size_t)(n0 + r) * DM + lseg * 8];
        lA[c] = &As[32 * c + 8 * w][0];    // wave-uniform LDS bases
        lB[c] = &Bs[32 * c + 8 * w][0];
    }
    int sw = l16 & 7;                      // read-side swizzle (row&7 = l16&7)

    for (int k0 = 0; k0 < DM; k0 += 64) {
#pragma unroll
        for (int c = 0; c < 4; c++) {
            gload16(gA[c] + k0, lA[c]);
            gload16(gB[c] + k0, lB[c]);
        }
        __syncthreads();
#pragma unroll
        for (int kk = 0; kk < 2; kk++) {
            bf16x8 af[4], bf[4];
#pragma unroll
            for (int i = 0; i < 4; i++)
                af[i] = *reinterpret_cast<const bf16x8*>(
                    &As[wm + i * 16 + l16][((kk * 4 + quad) ^ sw) << 3]);
#pragma unroll
            for (int j = 0; j < 4; j++)
                bf[j] = *reinterpret_cast<const bf16x8*>(
                    &Bs[wn + j * 16 + l16][((kk * 4 + quad) ^ sw) << 3]);
#pragma unroll
            for (int i = 0; i < 4; i++)
#pragma unroll
                for (int j = 0; j < 4; j++)
                    acc[i][j] = __builtin_amdgcn_mfma_f32_16x16x32_bf16(
                        af[i], bf[j], acc[i][j], 0, 0, 0);
        }
        __syncthreads();
    }
}

// GEMM1: zn @ w_qkv(reordered) -> Q,K [b,h,n,d] (Q pre-scaled), V^T [b,h,d,n].
// 1D grid, id = n*64 + m  ->  id%8 = m%8: same-A-row blocks share an XCD
// (A row-tile 256 KB x 8 rows = 2 MB, L2-resident).
__global__ __launch_bounds__(256) void gemm_qkv(
    const ushort* __restrict__ A,    // zn [M][DM]
    const ushort* __restrict__ BT,   // w_qkv^T reordered [3*DM][DM]
    ushort* __restrict__ Q, ushort* __restrict__ K, ushort* __restrict__ V) {
    __shared__ ushort smem[16384];   // As[128][64] | Bs[128][64]; Cs aliases
    ushort (*As)[64] = (ushort(*)[64])smem;
    ushort (*Bs)[64] = (ushort(*)[64])(smem + 8192);
    ushort* Cs = smem;               // QK view: [64][136]; V view: [128][72]
    int t = threadIdx.x;
    int id = blockIdx.x;
    int m0 = (id & 63) * 128, n0 = (id >> 6) * 128;
    floatx4 acc[4][4];
    gemm128_core(A, BT, m0, n0, t, acc, As, Bs);
    int lane = t & 63, w = t >> 6;
    int l16 = lane & 15, quad = lane >> 4;
    int wn = (w & 1) * 64;
    int which = n0 >> 10;            // 0=Q 1=K 2=V
    int hd0 = n0 & 1023;
    float scale = (which == 0) ? QSCALE : 1.0f;
    int bb = m0 >> 11;               // batch (blocks never cross batch)
    int nb = m0 & 2047;
    ushort* dstQK = (which == 0) ? Q : K;

#pragma unroll
    for (int p = 0; p < 2; p++) {    // row-half passes
        __syncthreads();
        if ((w >> 1) == p) {         // the 2 waves owning rows p*64..p*64+63
            if (which < 2) {
#pragma unroll
                for (int i = 0; i < 4; i++)
#pragma unroll
                    for (int j = 0; j < 4; j++)
#pragma unroll
                        for (int r = 0; r < 4; r++)
                            Cs[(i * 16 + quad * 4 + r) * 136 + wn + j * 16 + l16] =
                                f2b(acc[i][j][r] * scale);
            } else {                 // transposed bounce: Cs_v[dcol][n_local]
#pragma unroll
                for (int i = 0; i < 4; i++)
#pragma unroll
                    for (int j = 0; j < 4; j++)
#pragma unroll
                        for (int r = 0; r < 4; r++)
                            Cs[(wn + j * 16 + l16) * 72 + i * 16 + quad * 4 + r] =
                                f2b(acc[i][j][r]);
            }
        }
        __syncthreads();
        if (which < 2) {
            int ch = (t & 15) * 8;   // col chunk base
#pragma unroll
            for (int u = 0; u < 4; u++) {
                int lr = (t >> 4) + u * 16;
                int n = nb + p * 64 + lr;
                int hh = (hd0 + ch) >> 6, dd = ch & 63;
                *reinterpret_cast<uint4*>(
                    &dstQK[((size_t)((bb * NH + hh) * SEQ) + n) * HD + dd]) =
                    *reinterpret_cast<const uint4*>(&Cs[lr * 136 + ch]);
            }
        } else {
            int nch = (t & 7) * 8;
#pragma unroll
            for (int u = 0; u < 4; u++) {
                int dc = (t >> 3) + u * 32;
                int hh = (hd0 >> 6) + (dc >> 6), dd = dc & 63;
                int n = nb + p * 64 + nch;
                *reinterpret_cast<uint4*>(
                    &V[((size_t)((bb * NH + hh) * HD) + dd) * SEQ + n]) =
                    *reinterpret_cast<const uint4*>(&Cs[dc * 72 + nch]);
            }
        }
    }
}

// GEMM2: O @ w_proj + b_proj + z -> out (fp32).  1D grid, id%8 = m%8:
// A and B tiles both L2-resident per XCD (2 MB each).
__global__ __launch_bounds__(256) void gemm_proj(
    const ushort* __restrict__ A,    // O [M][DM]
    const ushort* __restrict__ BT,   // w_proj^T [DM][DM]
    const float* __restrict__ bias, const float* __restrict__ z,
    float* __restrict__ out) {
    __shared__ ushort As[128][64];
    __shared__ ushort Bs[128][64];
    int t = threadIdx.x;
    int id = blockIdx.x;
    int m0 = (id & 63) * 128, n0 = (id >> 6) * 128;
    floatx4 acc[4][4];
    gemm128_core(A, BT, m0, n0, t, acc, As, Bs);
    int lane = t & 63, w = t >> 6;
    int l16 = lane & 15, quad = lane >> 4;
    int wm = (w >> 1) * 64, wn = (w & 1) * 64;
#pragma unroll
    for (int j = 0; j < 4; j++) {
        int col = n0 + wn + j * 16 + l16;
        float bz = bias[col];
#pragma unroll
        for (int i = 0; i < 4; i++) {
#pragma unroll
            for (int r = 0; r < 4; r++) {
                int row = m0 + wm + i * 16 + quad * 4 + r;
                out[(size_t)row * DM + col] =
                    acc[i][j][r] + bz + z[(size_t)row * DM + col];
            }
        }
    }
}

// --------------------------------------------------------- Flash attention
// One block per (b,h, 128-row Q tile); wave owns 32 q-rows (2 groups of 16).
// Single-buffered K/V + register prefetch of the next tile.  LDS = 32 KB.
// P-swizzle fix (this round): XOR row-bit-3 (hi4) into the P column segment
// on BOTH the P-write and the ap-read.  Bank math: row stride 128 B ==
// 0 mod 32 banks, and swl=l16&7 repeats for l16>=8, so the b64 P-writes
// were 4-way bank-conflicted (the measured 4.19M SQ_LDS_BANK_CONFLICT =
// 128 cyc/block-iter).  hi4 splits them to 2-way (free, m136).  Bijective
// per-row permutation; write/read use the same mask -> math unchanged.
// Block id = qt*64 + bh -> id%8 = bh%8: same-head blocks share an XCD's L2.
__global__ __launch_bounds__(256) void attn_kernel(
    const ushort* __restrict__ Q, const ushort* __restrict__ K,
    const ushort* __restrict__ Vt, ushort* __restrict__ O) {
    __shared__ ushort QsPs[128 * 64];     // Q staging, then P [q][key] swizzled
    __shared__ ushort Ks[64 * 64];        // [key][d] swizzled (single buffer)
    __shared__ ushort Vs[64 * 64];        // [d][key] swizzled (single buffer)
    int t = threadIdx.x;
    int lane = t & 63, w = t >> 6;
    int l16 = lane & 15, quad = lane >> 4;
    int id = blockIdx.x;
    int qt = id >> 6, bh = id & 63;       // id%8 = bh%8 (XCD swizzle)
    int bb = bh >> 4, h = bh & 15;
    int q0 = qt * 128;
    const ushort* Qg = Q  + (size_t)((bb * NH + h) * SEQ + q0) * HD;
    const ushort* Kg = K  + (size_t)((bb * NH + h) * SEQ) * HD;
    const ushort* Vg = Vt + (size_t)((bb * NH + h) * HD) * SEQ;

    int srow = lane >> 3;                 // row within wave chunk (0..7)
    int lseg = (lane & 7) ^ srow;         // logical k-segment (XOR swizzle)
    int r0 = 8 * w + srow;                // row within 32-row chunk

    // Q staging (DMA, once) + K/V tile 0 (DMA)
    gload16(Qg + (size_t)r0 * HD + lseg * 8,         &QsPs[w * 512]);
    gload16(Qg + (size_t)(32 + r0) * HD + lseg * 8,  &QsPs[2048 + w * 512]);
    gload16(Qg + (size_t)(64 + r0) * HD + lseg * 8,  &QsPs[4096 + w * 512]);
    gload16(Qg + (size_t)(96 + r0) * HD + lseg * 8,  &QsPs[6144 + w * 512]);
    gload16(Kg + (size_t)r0 * HD + lseg * 8,         &Ks[w * 512]);
    gload16(Kg + (size_t)(32 + r0) * HD + lseg * 8,  &Ks[2048 + w * 512]);
    gload16(Vg + (size_t)r0 * SEQ + lseg * 8,        &Vs[w * 512]);
    gload16(Vg + (size_t)(32 + r0) * SEQ + lseg * 8, &Vs[2048 + w * 512]);
    __syncthreads();

    int swl = l16 & 7;                    // read-side swizzle (row&7 = l16&7)
    int hi4 = (l16 >> 3) << 2;            // row-bit-3 -> P column swizzle
    bf16x8 aq[2][2];
    ushort* PsRow[2];
#pragma unroll
    for (int g = 0; g < 2; g++) {
        int row = 32 * w + 16 * g + l16;
        aq[g][0] = *reinterpret_cast<const bf16x8*>(&QsPs[row * 64 + ((quad ^ swl) << 3)]);
        aq[g][1] = *reinterpret_cast<const bf16x8*>(&QsPs[row * 64 + (((quad + 4) ^ swl) << 3)]);
        PsRow[g] = &QsPs[row * 64];
    }

    // per-thread prefetch source offsets (tile-relative) and LDS commit slots
    size_t koff1 = (size_t)r0 * HD + lseg * 8;
    size_t koff2 = (size_t)(32 + r0) * HD + lseg * 8;
    size_t voff1 = (size_t)r0 * SEQ + lseg * 8;
    size_t voff2 = (size_t)(32 + r0) * SEQ + lseg * 8;
    ushort* kw1 = &Ks[w * 512 + (lane & 63) * 8];
    ushort* kw2 = &Ks[2048 + w * 512 + (lane & 63) * 8];
    ushort* vw1 = &Vs[w * 512 + (lane & 63) * 8];
    ushort* vw2 = &Vs[2048 + w * 512 + (lane & 63) * 8];
    const ushort* Kp = Kg + (size_t)64 * HD;   // next-tile base (tile 1)
    const ushort* Vp = Vg + 64;

    bf16x8 bones;
    {
        union { ushort u[8]; bf16x8 v; } cvt;
        ushort one = (l16 == 0) ? (ushort)0x3F80 : (ushort)0;
#pragma unroll
        for (int i = 0; i < 8; i++) cvt.u[i] = one;
        bones = cvt.v;
    }

    floatx4 Oacc[2][4], lacc[2];
#pragma unroll
    for (int g = 0; g < 2; g++) {
        lacc[g] = (floatx4){0.f, 0.f, 0.f, 0.f};
#pragma unroll
        for (int tt = 0; tt < 4; tt++) Oacc[g][tt] = (floatx4){0.f, 0.f, 0.f, 0.f};
    }

    constexpr int NT = SEQ / 64;
    for (int kt = 0; kt < NT; kt++) {
        // register prefetch of tile kt+1 (one-past read on last iter is
        // in-bounds of the workspace and never consumed)
        uint4 kr1 = *reinterpret_cast<const uint4*>(Kp + koff1);
        uint4 kr2 = *reinterpret_cast<const uint4*>(Kp + koff2);
        uint4 vr1 = *reinterpret_cast<const uint4*>(Vp + voff1);
        uint4 vr2 = *reinterpret_cast<const uint4*>(Vp + voff2);
        Kp += (size_t)64 * HD;
        Vp += 64;

        // S^T = K Q^T: 64 keys x 32 q per wave; K frags shared across groups.
        floatx4 sacc[2][4];
#pragma unroll
        for (int nt = 0; nt < 4; nt++) {
            bf16x8 ak0 = *reinterpret_cast<const bf16x8*>(&Ks[(nt * 16 + l16) * 64 + ((quad ^ swl) << 3)]);
            bf16x8 ak1 = *reinterpret_cast<const bf16x8*>(&Ks[(nt * 16 + l16) * 64 + (((quad + 4) ^ swl) << 3)]);
#pragma unroll
            for (int g = 0; g < 2; g++) {
                floatx4 sv = (floatx4){0.f, 0.f, 0.f, 0.f};
                sv = __builtin_amdgcn_mfma_f32_16x16x32_bf16(ak0, aq[g][0], sv, 0, 0, 0);
                sv = __builtin_amdgcn_mfma_f32_16x16x32_bf16(ak1, aq[g][1], sv, 0, 0, 0);
                sacc[g][nt] = sv;
            }
        }
        // p = exp2(S^T); truncate-pack pairs; write P[q][key] swizzled b64
#pragma unroll
        for (int g = 0; g < 2; g++) {
#pragma unroll
            for (int nt = 0; nt < 4; nt++) {
                float p0 = __builtin_amdgcn_exp2f(sacc[g][nt][0]);
                float p1 = __builtin_amdgcn_exp2f(sacc[g][nt][1]);
                float p2 = __builtin_amdgcn_exp2f(sacc[g][nt][2]);
                float p3 = __builtin_amdgcn_exp2f(sacc[g][nt][3]);
                uint b0, b1, b2, b3;
                __builtin_memcpy(&b0, &p0, 4); __builtin_memcpy(&b1, &p1, 4);
                __builtin_memcpy(&b2, &p2, 4); __builtin_memcpy(&b3, &p3, 4);
                uint2 pk;
                pk.x = __builtin_amdgcn_perm(b1, b0, 0x07060302u);  // truncate-pack
                pk.y = __builtin_amdgcn_perm(b3, b2, 0x07060302u);
                int lseg2 = 2 * nt + (quad >> 1);
                *reinterpret_cast<uint2*>(
                    &PsRow[g][((lseg2 ^ swl ^ hi4) << 3) + (quad & 1) * 4]) = pk;
            }
        }
        // O += P V ; row-sums via ones-column MFMA; V frags shared across groups
#pragma unroll
        for (int ks = 0; ks < 2; ks++) {
            bf16x8 ap[2];
#pragma unroll
            for (int g = 0; g < 2; g++) {
                ap[g] = *reinterpret_cast<const bf16x8*>(
                    &PsRow[g][(((4 * ks + quad) ^ swl ^ hi4) << 3)]);
                lacc[g] = __builtin_amdgcn_mfma_f32_16x16x32_bf16(ap[g], bones, lacc[g], 0, 0, 0);
            }
#pragma unroll
            for (int tt = 0; tt < 4; tt++) {
                bf16x8 bv = *reinterpret_cast<const bf16x8*>(
                    &Vs[(tt * 16 + l16) * 64 + ((((ks * 4 + quad)) ^ swl) << 3)]);
#pragma unroll
                for (int g = 0; g < 2; g++)
                    Oacc[g][tt] = __builtin_amdgcn_mfma_f32_16x16x32_bf16(ap[g], bv, Oacc[g][tt], 0, 0, 0);
            }
        }
        __syncthreads();              // all waves done reading Ks/Vs
        *reinterpret_cast<uint4*>(kw1) = kr1;
        *reinterpret_cast<uint4*>(kw2) = kr2;
        *reinterpret_cast<uint4*>(vw1) = vr1;
        *reinterpret_cast<uint4*>(vw2) = vr2;
        __syncthreads();              // next tile visible
    }
    float lq[2][4];
#pragma unroll
    for (int g = 0; g < 2; g++)
#pragma unroll
        for (int j = 0; j < 4; j++) lq[g][j] = __shfl(lacc[g][j], quad << 4);

#pragma unroll
    for (int g = 0; g < 2; g++) {
#pragma unroll
        for (int tt = 0; tt < 4; tt++) {
#pragma unroll
            for (int j = 0; j < 4; j++) {
                int n = q0 + 32 * w + 16 * g + quad * 4 + j;
                int dcol = tt * 16 + l16;
                float val = Oacc[g][tt][j] / lq[g][j];
                O[(size_t)(bb * SEQ + n) * DM + h * HD + dcol] = f2b(val);
            }
        }
    }
}

extern "C" void kernel_launch(void* const* d_in, const int* in_sizes, int n_in,
                              void* d_out, int out_size, void* d_ws, size_t ws_size,
                              hipStream_t stream) {
    const float* z      = (const float*)d_in[0];
    const float* gamma  = (const float*)d_in[1];
    const float* beta   = (const float*)d_in[2];
    const float* w_qkv  = (const float*)d_in[3];
    const float* w_proj = (const float*)d_in[4];
    const float* b_proj = (const float*)d_in[5];
    float* out = (float*)d_out;

    char* ws = (char*)d_ws;
    const size_t SZ = (size_t)M * DM * sizeof(ushort);   // 16 MiB
    ushort* zn   = (ushort*)(ws);                        // reused as attn output O
    ushort* Qb   = (ushort*)(ws + SZ);
    ushort* Kb   = (ushort*)(ws + 2 * SZ);
    ushort* Vb   = (ushort*)(ws + 3 * SZ);               // transposed [b,h,d,n]
    ushort* wqT  = (ushort*)(ws + 4 * SZ);               // reordered [3*DM][DM]
    ushort* wpT  = (ushort*)(ws + 4 * SZ + (size_t)DM * NQKV * sizeof(ushort));
    ushort* Ob = zn;   // zn dead after gemm_qkv

    prep_kernel<<<1024 + M, 256, 0, stream>>>(w_qkv, wqT, w_proj, wpT,
                                              z, gamma, beta, zn);
    gemm_qkv<<<(NQKV / 128) * 64, 256, 0, stream>>>(zn, wqT, Qb, Kb, Vb);
    attn_kernel<<<(SEQ / 128) * BATCH * NH, 256, 0, stream>>>(Qb, Kb, Vb, Ob);
    gemm_proj<<<(DM / 128) * 64, 256, 0, stream>>>(Ob, wpT, b_proj, z, out);
}